// Round 4
// baseline (2235.460 us; speedup 1.0000x reference)
//
#include <hip/hip_runtime.h>
#include <hip/hip_cooperative_groups.h>
#include <cstdint>
#include <cstddef>

namespace cg = cooperative_groups;

#define T_STEPS 20
#define N_PED   256
#define NG      16384   /* N_PED*G2 floats per grid row */

// XOR-swizzled LDS index for 64-wide K tiles (k in 0..63), 4-float blocks.
__device__ __forceinline__ int swz64(int row, int k) {
    return row * 64 + ((((k >> 2) ^ (row & 15)) << 2) | (k & 3));
}

// ---------------- Kernel P: one-time precompute ----------------
// bids 0..1279  : pg[t][p][j] = b_ih[j]+b_hh[j] + sum_e relu(xy@W_in.T+b_in)[e]*W_ih[j][e]
// bids 1280..1295: init h0,c0; W_ihT[e*512+j]=W_ih[j][64+e]; W_hhT[h*512+j]=W_hh[j][h]
__global__ __launch_bounds__(256) void kP(
    const float* __restrict__ scene, const float* __restrict__ hidden,
    const float* __restrict__ cell,  const float* __restrict__ W_in,
    const float* __restrict__ b_in,  const float* __restrict__ W_ih,
    const float* __restrict__ b_ih,  const float* __restrict__ b_hh,
    const float* __restrict__ W_hh,
    float* __restrict__ pg, float* __restrict__ h0, float* __restrict__ c0,
    float* __restrict__ W_ihT, float* __restrict__ W_hhT)
{
    int bid = blockIdx.x, tid = threadIdx.x;
    if (bid >= 1280) {
        int gid = (bid - 1280) * 256 + tid;
        for (int u = gid; u < 32768; u += 4096) {
            h0[u] = hidden[u];
            c0[u] = cell[u];
            int e = u >> 9, j = u & 511;
            W_ihT[u] = W_ih[j * 128 + 64 + e];
        }
        for (int u = gid; u < 65536; u += 4096) {
            int h = u >> 9, j = u & 511;
            W_hhT[u] = W_hh[j * 128 + h];
        }
        return;
    }
    __shared__ float ie[16 * 64];
    __shared__ float wih[128 * 65];
    int tb = bid >> 6;
    int p0 = ((bid >> 2) & 15) * 16;
    int j0 = (bid & 3) * 128;

    for (int k = 0; k < 8; ++k) {
        int fl = (tid + k * 256) * 4;
        int j_loc = fl >> 6, e0 = fl & 63;
        float4 v = *(const float4*)(W_ih + (size_t)(j0 + j_loc) * 128 + e0);
        wih[j_loc * 65 + e0 + 0] = v.x;
        wih[j_loc * 65 + e0 + 1] = v.y;
        wih[j_loc * 65 + e0 + 2] = v.z;
        wih[j_loc * 65 + e0 + 3] = v.w;
    }
    {
        int pp = tid >> 4, e0 = (tid & 15) * 4;
        size_t sbase = ((size_t)tb * N_PED + (p0 + pp)) * 3;
        float x = scene[sbase + 1];
        float y = scene[sbase + 2];
        #pragma unroll
        for (int i = 0; i < 4; ++i) {
            int e = e0 + i;
            float v = b_in[e] + x * W_in[e * 2 + 0] + y * W_in[e * 2 + 1];
            ie[pp * 64 + e] = v > 0.f ? v : 0.f;
        }
    }
    __syncthreads();
    for (int k = 0; k < 8; ++k) {
        int u = k * 256 + tid;
        int pp = u >> 7, j_loc = u & 127;
        int j = j0 + j_loc;
        float s = b_ih[j] + b_hh[j];
        #pragma unroll 8
        for (int e = 0; e < 64; ++e)
            s = fmaf(ie[pp * 64 + e], wih[j_loc * 65 + e], s);
        pg[((size_t)tb * N_PED + (p0 + pp)) * 512 + j] = s;
    }
}

// ---------------- Kernel C: one-time grid compaction ----------------
__global__ __launch_bounds__(256) void kC(
    const float* __restrict__ grids, int* __restrict__ counts,
    unsigned short* __restrict__ gidx)
{
    int r = blockIdx.x;              // t*256+p
    int tid = threadIdx.x, lane = tid & 63, w = tid >> 6;
    __shared__ unsigned short st[4][1024];
    __shared__ int wcnts[4];
    const float* row = grids + (size_t)r * NG;
    int wcnt = 0;
    for (int rd = 0; rd < 16; ++rd) {
        int fb = w * 4096 + rd * 256 + lane * 4;
        float4 v = *(const float4*)(row + fb);
        #pragma unroll
        for (int c = 0; c < 4; ++c) {
            float val = (c == 0) ? v.x : (c == 1) ? v.y : (c == 2) ? v.z : v.w;
            unsigned long long m = __ballot(val != 0.0f);
            if (val != 0.0f) {
                int pos = wcnt + (int)__popcll(m & ((1ull << lane) - 1ull));
                st[w][pos] = (unsigned short)(fb + c);
            }
            wcnt += (int)__popcll(m);
        }
    }
    if (lane == 0) wcnts[w] = wcnt;
    __syncthreads();
    int base = 0;
    #pragma unroll
    for (int i = 0; i < 4; ++i) if (i < w) base += wcnts[i];
    for (int k = lane; k < wcnt; k += 64)
        gidx[(size_t)r * 1024 + base + k] = st[w][k];
    if (tid == 0) counts[r] = wcnts[0] + wcnts[1] + wcnts[2] + wcnts[3];
}

// ---------------- kStep: fused 20-step recurrence (cooperative) ----------------
// grid = 256 blocks x 512 threads, 1 block/CU.
// Phase A (per step): block (o0=bid>>6, g=bid&63) computes A[o0..o0+63][g*64..+63]
//   = h_tile(64x128) @ W_t_tile(128x64); split-K across wave-halves + LDS reduce.
// Phase B: block p = bid does sparse gather of A rows + gates + LSTM pointwise.
__global__ __launch_bounds__(512) void kStep(
    const int* __restrict__ counts, const unsigned short* __restrict__ gidx,
    const float* __restrict__ W_t,  const float* __restrict__ pg,
    const float* __restrict__ W_ihT, const float* __restrict__ W_hhT,
    const float* __restrict__ b_t,  const float* __restrict__ W_out,
    const float* __restrict__ b_out,
    float* __restrict__ hbuf, float* __restrict__ cbuf,
    float* __restrict__ A, float* __restrict__ out)
{
    cg::grid_group gg = cg::this_grid();
    __shared__ float smem[16384];   // 64 KB
    int bid = blockIdx.x, tid = threadIdx.x;
    int lane = tid & 63, w = tid >> 6;

    for (int t = 0; t < T_STEPS; ++t) {
        const float* h  = hbuf + (t & 1) * 32768;
        const float* c  = cbuf + (t & 1) * 32768;
        float*       hn = hbuf + ((t + 1) & 1) * 32768;
        float*       cn = cbuf + ((t + 1) & 1) * 32768;

        // ================= Phase A =================
        {
            int o0 = (bid >> 6) * 64, g = bid & 63;
            #pragma unroll
            for (int i = 0; i < 8; ++i) {
                int u = i * 512 + tid;           // float4 unit 0..4095
                if (u < 2048) {
                    int kh = u >> 10, rem = u & 1023, r = rem >> 4, k4 = (rem & 15) * 4;
                    float4 v = *(const float4*)(h + (size_t)(o0 + r) * 128 + kh * 64 + k4);
                    *(float4*)&smem[kh * 4096 + swz64(r, k4)] = v;
                } else {
                    int v2 = u - 2048;
                    int kh = v2 >> 10, rem = v2 & 1023, e = rem >> 4, k4 = (rem & 15) * 4;
                    float4 v = *(const float4*)(W_t + (size_t)e * 8192 + g * 128 + kh * 64 + k4);
                    *(float4*)&smem[8192 + kh * 4096 + swz64(e, k4)] = v;
                }
            }
            __syncthreads();
            int kh = w >> 2, wq = w & 3;
            int wrow = (wq >> 1) * 32, wcol = (wq & 1) * 32;
            int lr = (lane >> 3) * 4, lc = (lane & 7) * 4;
            const float* hsb = &smem[kh * 4096];
            const float* wtb = &smem[8192 + kh * 4096];
            float acc[4][4] = {};
            #pragma unroll
            for (int k4i = 0; k4i < 16; ++k4i) {
                int kd = k4i * 4;
                float4 a[4], b[4];
                #pragma unroll
                for (int i = 0; i < 4; ++i) a[i] = *(const float4*)&hsb[swz64(wrow + lr + i, kd)];
                #pragma unroll
                for (int j = 0; j < 4; ++j) b[j] = *(const float4*)&wtb[swz64(wcol + lc + j, kd)];
                #pragma unroll
                for (int i = 0; i < 4; ++i)
                    #pragma unroll
                    for (int j = 0; j < 4; ++j) {
                        acc[i][j] = fmaf(a[i].x, b[j].x, acc[i][j]);
                        acc[i][j] = fmaf(a[i].y, b[j].y, acc[i][j]);
                        acc[i][j] = fmaf(a[i].z, b[j].z, acc[i][j]);
                        acc[i][j] = fmaf(a[i].w, b[j].w, acc[i][j]);
                    }
            }
            __syncthreads();
            if (kh == 1) {
                #pragma unroll
                for (int i = 0; i < 4; ++i) {
                    int row = wrow + lr + i;
                    int col = (wcol + lc) ^ (((row >> 2) & 7) << 3);
                    *(float4*)&smem[row * 64 + col] =
                        make_float4(acc[i][0], acc[i][1], acc[i][2], acc[i][3]);
                }
            }
            __syncthreads();
            if (kh == 0) {
                #pragma unroll
                for (int i = 0; i < 4; ++i) {
                    int row = wrow + lr + i;
                    int col = (wcol + lc) ^ (((row >> 2) & 7) << 3);
                    float4 r4 = *(const float4*)&smem[row * 64 + col];
                    float4 o4 = make_float4(acc[i][0] + r4.x, acc[i][1] + r4.y,
                                            acc[i][2] + r4.z, acc[i][3] + r4.w);
                    *(float4*)&A[(size_t)(o0 + row) * 4096 + g * 64 + wcol + lc] = o4;
                }
            }
        }
        gg.sync();

        // ================= Phase B =================
        {
            int p = bid, r = t * N_PED + p;
            unsigned short* lidx = (unsigned short*)smem;   // 1024 u16 (512 floats)
            float* part = smem + 512;                        // 8*64
            float* ten  = smem + 1024;                       // 64
            float* gts  = smem + 1088;                       // 512
            float* h2s  = smem + 1600;                       // 128
            float* hcur = smem + 1728;                       // 128
            int cnt = counts[r];
            ((unsigned int*)lidx)[tid] = ((const unsigned int*)(gidx + (size_t)r * 1024))[tid];
            if (tid < 128) hcur[tid] = h[p * 128 + tid];
            __syncthreads();

            float acc = 0.f;
            int k = w;
            for (; k + 24 < cnt; k += 32) {
                int i0 = lidx[k], i1 = lidx[k + 8], i2 = lidx[k + 16], i3 = lidx[k + 24];
                float a0 = A[(size_t)i0 * 64 + lane];
                float a1 = A[(size_t)i1 * 64 + lane];
                float a2 = A[(size_t)i2 * 64 + lane];
                float a3 = A[(size_t)i3 * 64 + lane];
                acc += a0; acc += a1; acc += a2; acc += a3;
            }
            for (; k < cnt; k += 8)
                acc += A[(size_t)lidx[k] * 64 + lane];
            part[w * 64 + lane] = acc;
            __syncthreads();

            if (tid < 64) {
                float s = b_t[tid];
                #pragma unroll
                for (int ww = 0; ww < 8; ++ww) s += part[ww * 64 + tid];
                ten[tid] = s > 0.f ? s : 0.f;
            }
            __syncthreads();

            {
                int j = tid;
                float gj = pg[(size_t)r * 512 + j];
                #pragma unroll 8
                for (int e = 0; e < 64; ++e)
                    gj = fmaf(ten[e], W_ihT[e * 512 + j], gj);
                #pragma unroll 8
                for (int hd = 0; hd < 128; ++hd)
                    gj = fmaf(hcur[hd], W_hhT[hd * 512 + j], gj);
                gts[j] = gj;
            }
            __syncthreads();

            if (tid < 128) {
                float ig = gts[tid], fg = gts[128 + tid], ggt = gts[256 + tid], og = gts[384 + tid];
                float si = 1.f / (1.f + expf(-ig));
                float sf = 1.f / (1.f + expf(-fg));
                float so = 1.f / (1.f + expf(-og));
                float cold = c[p * 128 + tid];
                float c2 = sf * cold + si * tanhf(ggt);
                float h2 = so * tanhf(c2);
                cn[p * 128 + tid] = c2;
                hn[p * 128 + tid] = h2;
                h2s[tid] = h2;
                if (t == T_STEPS - 1) {
                    out[25600 + p * 128 + tid] = h2;   // h_fin
                    out[58368 + p * 128 + tid] = c2;   // c_fin
                }
            }
            __syncthreads();

            if (w < 5) {
                float s = h2s[lane] * W_out[w * 128 + lane]
                        + h2s[lane + 64] * W_out[w * 128 + 64 + lane];
                #pragma unroll
                for (int off = 32; off > 0; off >>= 1) s += __shfl_xor(s, off);
                if (lane == 0) out[(size_t)r * 5 + w] = s + b_out[w];
            }
        }
        gg.sync();
    }
}

extern "C" void kernel_launch(void* const* d_in, const int* in_sizes, int n_in,
                              void* d_out, int out_size, void* d_ws, size_t ws_size,
                              hipStream_t stream) {
    (void)in_sizes; (void)n_in; (void)out_size; (void)ws_size;
    const float* scene  = (const float*)d_in[0];
    const float* grids  = (const float*)d_in[1];
    const float* hidden = (const float*)d_in[2];
    const float* cell   = (const float*)d_in[3];
    const float* W_in  = (const float*)d_in[5];
    const float* b_in  = (const float*)d_in[6];
    const float* W_t   = (const float*)d_in[7];
    const float* b_t   = (const float*)d_in[8];
    const float* W_ih  = (const float*)d_in[9];
    const float* b_ih  = (const float*)d_in[10];
    const float* W_hh  = (const float*)d_in[11];
    const float* b_hh  = (const float*)d_in[12];
    const float* W_out = (const float*)d_in[13];
    const float* b_out = (const float*)d_in[14];

    float* ws   = (float*)d_ws;
    float* hbuf = ws;                    // 2 x 32768
    float* cbuf = ws + 65536;            // 2 x 32768
    float* A    = ws + 131072;           // 256*4096
    float* pg   = ws + 1310720;          // 20*256*512
    float* WT   = ws + 3932160;          // W_ihT 64*512
    int*   counts = (int*)(ws + 3964928);             // 5120 ints
    unsigned short* gidx = (unsigned short*)(ws + 3970048); // 5120*1024 u16 (2621440 floats)
    float* W_hhT = ws + 6591488;         // 128*512
    float* outf = (float*)d_out;

    hipLaunchKernelGGL(kC, dim3(5120), dim3(256), 0, stream,
                       grids, counts, gidx);
    hipLaunchKernelGGL(kP, dim3(1296), dim3(256), 0, stream,
                       scene, hidden, cell, W_in, b_in, W_ih, b_ih, b_hh, W_hh,
                       pg, hbuf, cbuf, WT, W_hhT);

    const int* counts_c = counts;
    const unsigned short* gidx_c = gidx;
    const float* WT_c = WT;
    const float* W_hhT_c = W_hhT;
    const float* pg_c = pg;
    void* args[] = {
        (void*)&counts_c, (void*)&gidx_c, (void*)&W_t, (void*)&pg_c,
        (void*)&WT_c, (void*)&W_hhT_c, (void*)&b_t, (void*)&W_out,
        (void*)&b_out, (void*)&hbuf, (void*)&cbuf, (void*)&A, (void*)&outf
    };
    hipLaunchCooperativeKernel((const void*)kStep, dim3(256), dim3(512),
                               args, 0, stream);
}

// Round 5
// 1374.382 us; speedup vs baseline: 1.6265x; 1.6265x over previous
//
#include <hip/hip_runtime.h>
#include <cstdint>
#include <cstddef>

#define T_STEPS 20
#define N_PED   256
#define NG      16384   /* N_PED*G2 floats per grid row */

// XOR-swizzled LDS index for 64-wide K tiles (k in 0..63), 4-float blocks.
__device__ __forceinline__ int swz64(int row, int k) {
    return row * 64 + ((((k >> 2) ^ (row & 15)) << 2) | (k & 3));
}

// device-scope (agent) relaxed helpers — per-instruction coherent, no L2 flush
__device__ __forceinline__ void st_agent_f2(float* p, float a, float b) {
    union { float f[2]; unsigned long long u; } cv;
    cv.f[0] = a; cv.f[1] = b;
    __hip_atomic_store((unsigned long long*)p, cv.u, __ATOMIC_RELAXED,
                       __HIP_MEMORY_SCOPE_AGENT);
}
__device__ __forceinline__ void ld_agent_f4(const float* p, float4* out) {
    union { unsigned long long u[2]; float4 f; } cv;
    cv.u[0] = __hip_atomic_load((const unsigned long long*)p, __ATOMIC_RELAXED,
                                __HIP_MEMORY_SCOPE_AGENT);
    cv.u[1] = __hip_atomic_load((const unsigned long long*)p + 1, __ATOMIC_RELAXED,
                                __HIP_MEMORY_SCOPE_AGENT);
    *out = cv.f;
}
__device__ __forceinline__ float ld_agent_f(const float* p) {
    return __hip_atomic_load(p, __ATOMIC_RELAXED, __HIP_MEMORY_SCOPE_AGENT);
}

// hand-rolled grid barrier: monotonic target, no L2 invalidation.
// pre-__syncthreads drains each wave's vmcnt (compiler emits s_waitcnt before
// s_barrier), so all sc1 stores are at L3 before the arrive.
__device__ __forceinline__ void gbar(unsigned int* bar, unsigned int target) {
    __syncthreads();
    if (threadIdx.x == 0) {
        __hip_atomic_fetch_add(bar, 1u, __ATOMIC_RELEASE, __HIP_MEMORY_SCOPE_AGENT);
        while (__hip_atomic_load(bar, __ATOMIC_RELAXED, __HIP_MEMORY_SCOPE_AGENT) < target)
            __builtin_amdgcn_s_sleep(2);
    }
    __syncthreads();
}

// ---------------- Kernel P: one-time precompute ----------------
__global__ __launch_bounds__(256) void kP(
    const float* __restrict__ scene, const float* __restrict__ hidden,
    const float* __restrict__ cell,  const float* __restrict__ W_in,
    const float* __restrict__ b_in,  const float* __restrict__ W_ih,
    const float* __restrict__ b_ih,  const float* __restrict__ b_hh,
    const float* __restrict__ W_hh,
    float* __restrict__ pg, float* __restrict__ h0, float* __restrict__ c0,
    float* __restrict__ W_ihT, float* __restrict__ W_hhT)
{
    int bid = blockIdx.x, tid = threadIdx.x;
    if (bid >= 1280) {
        int gid = (bid - 1280) * 256 + tid;
        for (int u = gid; u < 32768; u += 4096) {
            h0[u] = hidden[u];
            c0[u] = cell[u];
            int e = u >> 9, j = u & 511;
            W_ihT[u] = W_ih[j * 128 + 64 + e];
        }
        for (int u = gid; u < 65536; u += 4096) {
            int h = u >> 9, j = u & 511;
            W_hhT[u] = W_hh[j * 128 + h];
        }
        return;
    }
    __shared__ float ie[16 * 64];
    __shared__ float wih[128 * 65];
    int tb = bid >> 6;
    int p0 = ((bid >> 2) & 15) * 16;
    int j0 = (bid & 3) * 128;

    for (int k = 0; k < 8; ++k) {
        int fl = (tid + k * 256) * 4;
        int j_loc = fl >> 6, e0 = fl & 63;
        float4 v = *(const float4*)(W_ih + (size_t)(j0 + j_loc) * 128 + e0);
        wih[j_loc * 65 + e0 + 0] = v.x;
        wih[j_loc * 65 + e0 + 1] = v.y;
        wih[j_loc * 65 + e0 + 2] = v.z;
        wih[j_loc * 65 + e0 + 3] = v.w;
    }
    {
        int pp = tid >> 4, e0 = (tid & 15) * 4;
        size_t sbase = ((size_t)tb * N_PED + (p0 + pp)) * 3;
        float x = scene[sbase + 1];
        float y = scene[sbase + 2];
        #pragma unroll
        for (int i = 0; i < 4; ++i) {
            int e = e0 + i;
            float v = b_in[e] + x * W_in[e * 2 + 0] + y * W_in[e * 2 + 1];
            ie[pp * 64 + e] = v > 0.f ? v : 0.f;
        }
    }
    __syncthreads();
    for (int k = 0; k < 8; ++k) {
        int u = k * 256 + tid;
        int pp = u >> 7, j_loc = u & 127;
        int j = j0 + j_loc;
        float s = b_ih[j] + b_hh[j];
        #pragma unroll 8
        for (int e = 0; e < 64; ++e)
            s = fmaf(ie[pp * 64 + e], wih[j_loc * 65 + e], s);
        pg[((size_t)tb * N_PED + (p0 + pp)) * 512 + j] = s;
    }
}

// ---------------- Kernel C: one-time grid compaction (+ barrier init) ----------
__global__ __launch_bounds__(256) void kC(
    const float* __restrict__ grids, int* __restrict__ counts,
    unsigned short* __restrict__ gidx, unsigned int* __restrict__ bar)
{
    int r = blockIdx.x;              // t*256+p
    int tid = threadIdx.x, lane = tid & 63, w = tid >> 6;
    if (r == 0 && tid == 0) *bar = 0u;
    __shared__ unsigned short st[4][1024];
    __shared__ int wcnts[4];
    const float* row = grids + (size_t)r * NG;
    int wcnt = 0;
    for (int rd = 0; rd < 16; ++rd) {
        int fb = w * 4096 + rd * 256 + lane * 4;
        float4 v = *(const float4*)(row + fb);
        #pragma unroll
        for (int c = 0; c < 4; ++c) {
            float val = (c == 0) ? v.x : (c == 1) ? v.y : (c == 2) ? v.z : v.w;
            unsigned long long m = __ballot(val != 0.0f);
            if (val != 0.0f) {
                int pos = wcnt + (int)__popcll(m & ((1ull << lane) - 1ull));
                st[w][pos] = (unsigned short)(fb + c);
            }
            wcnt += (int)__popcll(m);
        }
    }
    if (lane == 0) wcnts[w] = wcnt;
    __syncthreads();
    int base = 0;
    #pragma unroll
    for (int i = 0; i < 4; ++i) if (i < w) base += wcnts[i];
    for (int k = lane; k < wcnt; k += 64)
        gidx[(size_t)r * 1024 + base + k] = st[w][k];
    if (tid == 0) counts[r] = wcnts[0] + wcnts[1] + wcnts[2] + wcnts[3];
}

// ---------------- kStep: fused 20-step recurrence (custom barrier) ------------
__global__ __launch_bounds__(512) void kStep(
    const int* __restrict__ counts, const unsigned short* __restrict__ gidx,
    const float* __restrict__ W_t,  const float* __restrict__ pg,
    const float* __restrict__ W_ihT, const float* __restrict__ W_hhT,
    const float* __restrict__ b_t,  const float* __restrict__ W_out,
    const float* __restrict__ b_out,
    float* __restrict__ hbuf, float* __restrict__ cbuf,
    float* __restrict__ A, float* __restrict__ out,
    unsigned int* __restrict__ bar)
{
    __shared__ float smem[16384];   // 64 KB
    int bid = blockIdx.x, tid = threadIdx.x;
    int lane = tid & 63, w = tid >> 6;
    unsigned int barn = 0;

    for (int t = 0; t < T_STEPS; ++t) {
        const float* h  = hbuf + (t & 1) * 32768;
        const float* c  = cbuf + (t & 1) * 32768;
        float*       hn = hbuf + ((t + 1) & 1) * 32768;
        float*       cn = cbuf + ((t + 1) & 1) * 32768;

        // ================= Phase A: A = h @ W_t-tile =================
        {
            int o0 = (bid >> 6) * 64, g = bid & 63;
            #pragma unroll
            for (int i = 0; i < 8; ++i) {
                int u = i * 512 + tid;           // float4 unit 0..4095
                if (u < 2048) {
                    int kh = u >> 10, rem = u & 1023, r = rem >> 4, k4 = (rem & 15) * 4;
                    float4 v;
                    ld_agent_f4(h + (size_t)(o0 + r) * 128 + kh * 64 + k4, &v);
                    *(float4*)&smem[kh * 4096 + swz64(r, k4)] = v;
                } else {
                    int v2 = u - 2048;
                    int kh = v2 >> 10, rem = v2 & 1023, e = rem >> 4, k4 = (rem & 15) * 4;
                    float4 v = *(const float4*)(W_t + (size_t)e * 8192 + g * 128 + kh * 64 + k4);
                    *(float4*)&smem[8192 + kh * 4096 + swz64(e, k4)] = v;
                }
            }
            __syncthreads();
            int kh = w >> 2, wq = w & 3;
            int wrow = (wq >> 1) * 32, wcol = (wq & 1) * 32;
            int lr = (lane >> 3) * 4, lc = (lane & 7) * 4;
            const float* hsb = &smem[kh * 4096];
            const float* wtb = &smem[8192 + kh * 4096];
            float acc[4][4] = {};
            #pragma unroll
            for (int k4i = 0; k4i < 16; ++k4i) {
                int kd = k4i * 4;
                float4 a[4], b[4];
                #pragma unroll
                for (int i = 0; i < 4; ++i) a[i] = *(const float4*)&hsb[swz64(wrow + lr + i, kd)];
                #pragma unroll
                for (int j = 0; j < 4; ++j) b[j] = *(const float4*)&wtb[swz64(wcol + lc + j, kd)];
                #pragma unroll
                for (int i = 0; i < 4; ++i)
                    #pragma unroll
                    for (int j = 0; j < 4; ++j) {
                        acc[i][j] = fmaf(a[i].x, b[j].x, acc[i][j]);
                        acc[i][j] = fmaf(a[i].y, b[j].y, acc[i][j]);
                        acc[i][j] = fmaf(a[i].z, b[j].z, acc[i][j]);
                        acc[i][j] = fmaf(a[i].w, b[j].w, acc[i][j]);
                    }
            }
            __syncthreads();
            if (kh == 1) {
                #pragma unroll
                for (int i = 0; i < 4; ++i) {
                    int row = wrow + lr + i;
                    int col = (wcol + lc) ^ (((row >> 2) & 7) << 3);
                    *(float4*)&smem[row * 64 + col] =
                        make_float4(acc[i][0], acc[i][1], acc[i][2], acc[i][3]);
                }
            }
            __syncthreads();
            if (kh == 0) {
                #pragma unroll
                for (int i = 0; i < 4; ++i) {
                    int row = wrow + lr + i;
                    int col = (wcol + lc) ^ (((row >> 2) & 7) << 3);
                    float4 r4 = *(const float4*)&smem[row * 64 + col];
                    float* dst = &A[(size_t)(o0 + row) * 4096 + g * 64 + wcol + lc];
                    st_agent_f2(dst + 0, acc[i][0] + r4.x, acc[i][1] + r4.y);
                    st_agent_f2(dst + 2, acc[i][2] + r4.z, acc[i][3] + r4.w);
                }
            }
        }
        gbar(bar, 256u * (++barn));

        // ================= Phase B: sparse pool + gates + LSTM =================
        {
            int p = bid, r = t * N_PED + p;
            unsigned short* lidx = (unsigned short*)smem;   // 1024 u16
            float* part = smem + 512;                        // 8*64
            float* ten  = smem + 1024;                       // 64
            float* gts  = smem + 1088;                       // 512
            float* h2s  = smem + 1600;                       // 128
            float* hcur = smem + 1728;                       // 128
            int cnt = counts[r];
            ((unsigned int*)lidx)[tid] = ((const unsigned int*)(gidx + (size_t)r * 1024))[tid];
            if (tid < 128) hcur[tid] = ld_agent_f(&h[p * 128 + tid]);
            __syncthreads();

            float acc = 0.f;
            int k = w;
            for (; k + 56 < cnt; k += 64) {
                int i0 = lidx[k],      i1 = lidx[k + 8],  i2 = lidx[k + 16], i3 = lidx[k + 24];
                int i4 = lidx[k + 32], i5 = lidx[k + 40], i6 = lidx[k + 48], i7 = lidx[k + 56];
                float a0 = ld_agent_f(&A[(size_t)i0 * 64 + lane]);
                float a1 = ld_agent_f(&A[(size_t)i1 * 64 + lane]);
                float a2 = ld_agent_f(&A[(size_t)i2 * 64 + lane]);
                float a3 = ld_agent_f(&A[(size_t)i3 * 64 + lane]);
                float a4 = ld_agent_f(&A[(size_t)i4 * 64 + lane]);
                float a5 = ld_agent_f(&A[(size_t)i5 * 64 + lane]);
                float a6 = ld_agent_f(&A[(size_t)i6 * 64 + lane]);
                float a7 = ld_agent_f(&A[(size_t)i7 * 64 + lane]);
                acc += a0 + a1; acc += a2 + a3; acc += a4 + a5; acc += a6 + a7;
            }
            for (; k < cnt; k += 8)
                acc += ld_agent_f(&A[(size_t)lidx[k] * 64 + lane]);
            part[w * 64 + lane] = acc;
            __syncthreads();

            if (tid < 64) {
                float s = b_t[tid];
                #pragma unroll
                for (int ww = 0; ww < 8; ++ww) s += part[ww * 64 + tid];
                ten[tid] = s > 0.f ? s : 0.f;
            }
            __syncthreads();

            {
                int j = tid;
                float gj = pg[(size_t)r * 512 + j];
                #pragma unroll 8
                for (int e = 0; e < 64; ++e)
                    gj = fmaf(ten[e], W_ihT[e * 512 + j], gj);
                #pragma unroll 8
                for (int hd = 0; hd < 128; ++hd)
                    gj = fmaf(hcur[hd], W_hhT[hd * 512 + j], gj);
                gts[j] = gj;
            }
            __syncthreads();

            if (tid < 128) {
                float ig = gts[tid], fg = gts[128 + tid], ggt = gts[256 + tid], og = gts[384 + tid];
                float si = 1.f / (1.f + expf(-ig));
                float sf = 1.f / (1.f + expf(-fg));
                float so = 1.f / (1.f + expf(-og));
                float cold = c[p * 128 + tid];
                float c2 = sf * cold + si * tanhf(ggt);
                float h2 = so * tanhf(c2);
                cn[p * 128 + tid] = c2;                 // block-local: normal store
                __hip_atomic_store(&hn[p * 128 + tid], h2, __ATOMIC_RELAXED,
                                   __HIP_MEMORY_SCOPE_AGENT);  // cross-block
                h2s[tid] = h2;
                if (t == T_STEPS - 1) {
                    out[25600 + p * 128 + tid] = h2;   // h_fin
                    out[58368 + p * 128 + tid] = c2;   // c_fin
                }
            }
            __syncthreads();

            if (w < 5) {
                float s = h2s[lane] * W_out[w * 128 + lane]
                        + h2s[lane + 64] * W_out[w * 128 + 64 + lane];
                #pragma unroll
                for (int off = 32; off > 0; off >>= 1) s += __shfl_xor(s, off);
                if (lane == 0) out[(size_t)r * 5 + w] = s + b_out[w];
            }
        }
        if (t != T_STEPS - 1) gbar(bar, 256u * (++barn));
    }
}

extern "C" void kernel_launch(void* const* d_in, const int* in_sizes, int n_in,
                              void* d_out, int out_size, void* d_ws, size_t ws_size,
                              hipStream_t stream) {
    (void)in_sizes; (void)n_in; (void)out_size; (void)ws_size;
    const float* scene  = (const float*)d_in[0];
    const float* grids  = (const float*)d_in[1];
    const float* hidden = (const float*)d_in[2];
    const float* cell   = (const float*)d_in[3];
    const float* W_in  = (const float*)d_in[5];
    const float* b_in  = (const float*)d_in[6];
    const float* W_t   = (const float*)d_in[7];
    const float* b_t   = (const float*)d_in[8];
    const float* W_ih  = (const float*)d_in[9];
    const float* b_ih  = (const float*)d_in[10];
    const float* W_hh  = (const float*)d_in[11];
    const float* b_hh  = (const float*)d_in[12];
    const float* W_out = (const float*)d_in[13];
    const float* b_out = (const float*)d_in[14];

    float* ws   = (float*)d_ws;
    float* hbuf = ws;                    // 2 x 32768
    float* cbuf = ws + 65536;            // 2 x 32768
    float* A    = ws + 131072;           // 256*4096
    float* pg   = ws + 1310720;          // 20*256*512
    float* WT   = ws + 3932160;          // W_ihT 64*512
    int*   counts = (int*)(ws + 3964928);             // 5120 ints
    unsigned short* gidx = (unsigned short*)(ws + 3970048); // 5120*1024 u16
    float* W_hhT = ws + 6591488;         // 128*512
    unsigned int* bar = (unsigned int*)(ws + 6657152); // own cache line
    float* outf = (float*)d_out;

    hipLaunchKernelGGL(kC, dim3(5120), dim3(256), 0, stream,
                       grids, counts, gidx, bar);
    hipLaunchKernelGGL(kP, dim3(1296), dim3(256), 0, stream,
                       scene, hidden, cell, W_in, b_in, W_ih, b_ih, b_hh, W_hh,
                       pg, hbuf, cbuf, WT, W_hhT);

    const int* counts_c = counts;
    const unsigned short* gidx_c = gidx;
    const float* WT_c = WT;
    const float* W_hhT_c = W_hhT;
    const float* pg_c = pg;
    void* args[] = {
        (void*)&counts_c, (void*)&gidx_c, (void*)&W_t, (void*)&pg_c,
        (void*)&WT_c, (void*)&W_hhT_c, (void*)&b_t, (void*)&W_out,
        (void*)&b_out, (void*)&hbuf, (void*)&cbuf, (void*)&A, (void*)&outf,
        (void*)&bar
    };
    hipLaunchCooperativeKernel((const void*)kStep, dim3(256), dim3(512),
                               args, 0, stream);
}

// Round 11
// 1220.096 us; speedup vs baseline: 1.8322x; 1.1265x over previous
//
#include <hip/hip_runtime.h>
#include <cstdint>
#include <cstddef>

#define T_STEPS 20
#define N_PED   256
#define NG      16384   /* N_PED*G2 floats per grid row */

// XOR-swizzled LDS index for 64-wide K tiles (k in 0..63), 4-float blocks.
__device__ __forceinline__ int swz64(int row, int k) {
    return row * 64 + ((((k >> 2) ^ (row & 15)) << 2) | (k & 3));
}

// device-scope (agent) relaxed helpers — per-instruction coherent, no L2 flush
__device__ __forceinline__ void st_agent_f2(float* p, float a, float b) {
    union { float f[2]; unsigned long long u; } cv;
    cv.f[0] = a; cv.f[1] = b;
    __hip_atomic_store((unsigned long long*)p, cv.u, __ATOMIC_RELAXED,
                       __HIP_MEMORY_SCOPE_AGENT);
}
__device__ __forceinline__ void ld_agent_f4(const float* p, float4* out) {
    union { unsigned long long u[2]; float4 f; } cv;
    cv.u[0] = __hip_atomic_load((const unsigned long long*)p, __ATOMIC_RELAXED,
                                __HIP_MEMORY_SCOPE_AGENT);
    cv.u[1] = __hip_atomic_load((const unsigned long long*)p + 1, __ATOMIC_RELAXED,
                                __HIP_MEMORY_SCOPE_AGENT);
    *out = cv.f;
}
__device__ __forceinline__ float ld_agent_f(const float* p) {
    return __hip_atomic_load(p, __ATOMIC_RELAXED, __HIP_MEMORY_SCOPE_AGENT);
}

// Hand-rolled grid barrier, FULLY RELAXED.
// Correctness: all cross-block data (A, h) is written with sc1 write-through
// stores; __syncthreads() before the arrive emits s_waitcnt vmcnt(0), so those
// stores are at the coherence point (L3) before the counter bumps. Consumers
// read A/h with sc1 loads (bypass L2), so no acquire/invalidate is needed.
// RELEASE here would emit buffer_wbl2 (full L2 writeback) per arrive — that
// was ~35 us/step in round 5.
__device__ __forceinline__ void gbar(unsigned int* bar, unsigned int target) {
    __syncthreads();
    if (threadIdx.x == 0) {
        __hip_atomic_fetch_add(bar, 1u, __ATOMIC_RELAXED, __HIP_MEMORY_SCOPE_AGENT);
        while (__hip_atomic_load(bar, __ATOMIC_RELAXED, __HIP_MEMORY_SCOPE_AGENT) < target)
            __builtin_amdgcn_s_sleep(1);
    }
    __syncthreads();
}

// ---------------- Kernel P: one-time precompute ----------------
__global__ __launch_bounds__(256) void kP(
    const float* __restrict__ scene, const float* __restrict__ hidden,
    const float* __restrict__ cell,  const float* __restrict__ W_in,
    const float* __restrict__ b_in,  const float* __restrict__ W_ih,
    const float* __restrict__ b_ih,  const float* __restrict__ b_hh,
    const float* __restrict__ W_hh,
    float* __restrict__ pg, float* __restrict__ h0, float* __restrict__ c0,
    float* __restrict__ W_ihT, float* __restrict__ W_hhT)
{
    int bid = blockIdx.x, tid = threadIdx.x;
    if (bid >= 1280) {
        int gid = (bid - 1280) * 256 + tid;
        for (int u = gid; u < 32768; u += 4096) {
            h0[u] = hidden[u];
            c0[u] = cell[u];
            int e = u >> 9, j = u & 511;
            W_ihT[u] = W_ih[j * 128 + 64 + e];
        }
        for (int u = gid; u < 65536; u += 4096) {
            int h = u >> 9, j = u & 511;
            W_hhT[u] = W_hh[j * 128 + h];
        }
        return;
    }
    __shared__ float ie[16 * 64];
    __shared__ float wih[128 * 65];
    int tb = bid >> 6;
    int p0 = ((bid >> 2) & 15) * 16;
    int j0 = (bid & 3) * 128;

    for (int k = 0; k < 8; ++k) {
        int fl = (tid + k * 256) * 4;
        int j_loc = fl >> 6, e0 = fl & 63;
        float4 v = *(const float4*)(W_ih + (size_t)(j0 + j_loc) * 128 + e0);
        wih[j_loc * 65 + e0 + 0] = v.x;
        wih[j_loc * 65 + e0 + 1] = v.y;
        wih[j_loc * 65 + e0 + 2] = v.z;
        wih[j_loc * 65 + e0 + 3] = v.w;
    }
    {
        int pp = tid >> 4, e0 = (tid & 15) * 4;
        size_t sbase = ((size_t)tb * N_PED + (p0 + pp)) * 3;
        float x = scene[sbase + 1];
        float y = scene[sbase + 2];
        #pragma unroll
        for (int i = 0; i < 4; ++i) {
            int e = e0 + i;
            float v = b_in[e] + x * W_in[e * 2 + 0] + y * W_in[e * 2 + 1];
            ie[pp * 64 + e] = v > 0.f ? v : 0.f;
        }
    }
    __syncthreads();
    for (int k = 0; k < 8; ++k) {
        int u = k * 256 + tid;
        int pp = u >> 7, j_loc = u & 127;
        int j = j0 + j_loc;
        float s = b_ih[j] + b_hh[j];
        #pragma unroll 8
        for (int e = 0; e < 64; ++e)
            s = fmaf(ie[pp * 64 + e], wih[j_loc * 65 + e], s);
        pg[((size_t)tb * N_PED + (p0 + pp)) * 512 + j] = s;
    }
}

// ---------------- Kernel C: one-time grid compaction (+ barrier init) ----------
__global__ __launch_bounds__(256) void kC(
    const float* __restrict__ grids, int* __restrict__ counts,
    unsigned short* __restrict__ gidx, unsigned int* __restrict__ bar)
{
    int r = blockIdx.x;              // t*256+p
    int tid = threadIdx.x, lane = tid & 63, w = tid >> 6;
    if (r == 0 && tid == 0) *bar = 0u;
    __shared__ unsigned short st[4][1024];
    __shared__ int wcnts[4];
    const float* row = grids + (size_t)r * NG;
    int wcnt = 0;
    for (int rd = 0; rd < 16; ++rd) {
        int fb = w * 4096 + rd * 256 + lane * 4;
        float4 v = *(const float4*)(row + fb);
        #pragma unroll
        for (int c = 0; c < 4; ++c) {
            float val = (c == 0) ? v.x : (c == 1) ? v.y : (c == 2) ? v.z : v.w;
            unsigned long long m = __ballot(val != 0.0f);
            if (val != 0.0f) {
                int pos = wcnt + (int)__popcll(m & ((1ull << lane) - 1ull));
                st[w][pos] = (unsigned short)(fb + c);
            }
            wcnt += (int)__popcll(m);
        }
    }
    if (lane == 0) wcnts[w] = wcnt;
    __syncthreads();
    int base = 0;
    #pragma unroll
    for (int i = 0; i < 4; ++i) if (i < w) base += wcnts[i];
    for (int k = lane; k < wcnt; k += 64)
        gidx[(size_t)r * 1024 + base + k] = st[w][k];
    if (tid == 0) counts[r] = wcnts[0] + wcnts[1] + wcnts[2] + wcnts[3];
}

// ---------------- kStep: fused 20-step recurrence (relaxed barrier) ------------
__global__ __launch_bounds__(512) void kStep(
    const int* __restrict__ counts, const unsigned short* __restrict__ gidx,
    const float* __restrict__ W_t,  const float* __restrict__ pg,
    const float* __restrict__ W_ihT, const float* __restrict__ W_hhT,
    const float* __restrict__ b_t,  const float* __restrict__ W_out,
    const float* __restrict__ b_out,
    float* __restrict__ hbuf, float* __restrict__ cbuf,
    float* __restrict__ A, float* __restrict__ out,
    unsigned int* __restrict__ bar)
{
    __shared__ float smem[16384];   // 64 KB
    int bid = blockIdx.x, tid = threadIdx.x;
    int lane = tid & 63, w = tid >> 6;
    unsigned int barn = 0;

    for (int t = 0; t < T_STEPS; ++t) {
        const float* h  = hbuf + (t & 1) * 32768;
        const float* c  = cbuf + (t & 1) * 32768;
        float*       hn = hbuf + ((t + 1) & 1) * 32768;
        float*       cn = cbuf + ((t + 1) & 1) * 32768;

        // ================= Phase A: A = h @ W_t-tile =================
        {
            int o0 = (bid >> 6) * 64, g = bid & 63;
            #pragma unroll
            for (int i = 0; i < 8; ++i) {
                int u = i * 512 + tid;           // float4 unit 0..4095
                if (u < 2048) {
                    int kh = u >> 10, rem = u & 1023, r = rem >> 4, k4 = (rem & 15) * 4;
                    float4 v;
                    ld_agent_f4(h + (size_t)(o0 + r) * 128 + kh * 64 + k4, &v);
                    *(float4*)&smem[kh * 4096 + swz64(r, k4)] = v;
                } else {
                    int v2 = u - 2048;
                    int kh = v2 >> 10, rem = v2 & 1023, e = rem >> 4, k4 = (rem & 15) * 4;
                    float4 v = *(const float4*)(W_t + (size_t)e * 8192 + g * 128 + kh * 64 + k4);
                    *(float4*)&smem[8192 + kh * 4096 + swz64(e, k4)] = v;
                }
            }
            __syncthreads();
            int kh = w >> 2, wq = w & 3;
            int wrow = (wq >> 1) * 32, wcol = (wq & 1) * 32;
            int lr = (lane >> 3) * 4, lc = (lane & 7) * 4;
            const float* hsb = &smem[kh * 4096];
            const float* wtb = &smem[8192 + kh * 4096];
            float acc[4][4] = {};
            #pragma unroll
            for (int k4i = 0; k4i < 16; ++k4i) {
                int kd = k4i * 4;
                float4 a[4], b[4];
                #pragma unroll
                for (int i = 0; i < 4; ++i) a[i] = *(const float4*)&hsb[swz64(wrow + lr + i, kd)];
                #pragma unroll
                for (int j = 0; j < 4; ++j) b[j] = *(const float4*)&wtb[swz64(wcol + lc + j, kd)];
                #pragma unroll
                for (int i = 0; i < 4; ++i)
                    #pragma unroll
                    for (int j = 0; j < 4; ++j) {
                        acc[i][j] = fmaf(a[i].x, b[j].x, acc[i][j]);
                        acc[i][j] = fmaf(a[i].y, b[j].y, acc[i][j]);
                        acc[i][j] = fmaf(a[i].z, b[j].z, acc[i][j]);
                        acc[i][j] = fmaf(a[i].w, b[j].w, acc[i][j]);
                    }
            }
            __syncthreads();
            if (kh == 1) {
                #pragma unroll
                for (int i = 0; i < 4; ++i) {
                    int row = wrow + lr + i;
                    int col = (wcol + lc) ^ (((row >> 2) & 7) << 3);
                    *(float4*)&smem[row * 64 + col] =
                        make_float4(acc[i][0], acc[i][1], acc[i][2], acc[i][3]);
                }
            }
            __syncthreads();
            if (kh == 0) {
                #pragma unroll
                for (int i = 0; i < 4; ++i) {
                    int row = wrow + lr + i;
                    int col = (wcol + lc) ^ (((row >> 2) & 7) << 3);
                    float4 r4 = *(const float4*)&smem[row * 64 + col];
                    float* dst = &A[(size_t)(o0 + row) * 4096 + g * 64 + wcol + lc];
                    st_agent_f2(dst + 0, acc[i][0] + r4.x, acc[i][1] + r4.y);
                    st_agent_f2(dst + 2, acc[i][2] + r4.z, acc[i][3] + r4.w);
                }
            }
        }
        gbar(bar, 256u * (++barn));

        // ================= Phase B: sparse pool + gates + LSTM =================
        {
            int p = bid, r = t * N_PED + p;
            unsigned short* lidx = (unsigned short*)smem;   // 1024 u16
            float* part = smem + 512;                        // 8*64
            float* ten  = smem + 1024;                       // 64
            float* gts  = smem + 1088;                       // 512
            float* h2s  = smem + 1600;                       // 128
            float* hcur = smem + 1728;                       // 128
            int cnt = counts[r];
            ((unsigned int*)lidx)[tid] = ((const unsigned int*)(gidx + (size_t)r * 1024))[tid];
            if (tid < 128) hcur[tid] = ld_agent_f(&h[p * 128 + tid]);
            __syncthreads();

            float acc = 0.f;
            int k = w;
            for (; k + 56 < cnt; k += 64) {
                int i0 = lidx[k],      i1 = lidx[k + 8],  i2 = lidx[k + 16], i3 = lidx[k + 24];
                int i4 = lidx[k + 32], i5 = lidx[k + 40], i6 = lidx[k + 48], i7 = lidx[k + 56];
                float a0 = ld_agent_f(&A[(size_t)i0 * 64 + lane]);
                float a1 = ld_agent_f(&A[(size_t)i1 * 64 + lane]);
                float a2 = ld_agent_f(&A[(size_t)i2 * 64 + lane]);
                float a3 = ld_agent_f(&A[(size_t)i3 * 64 + lane]);
                float a4 = ld_agent_f(&A[(size_t)i4 * 64 + lane]);
                float a5 = ld_agent_f(&A[(size_t)i5 * 64 + lane]);
                float a6 = ld_agent_f(&A[(size_t)i6 * 64 + lane]);
                float a7 = ld_agent_f(&A[(size_t)i7 * 64 + lane]);
                acc += a0 + a1; acc += a2 + a3; acc += a4 + a5; acc += a6 + a7;
            }
            for (; k < cnt; k += 8)
                acc += ld_agent_f(&A[(size_t)lidx[k] * 64 + lane]);
            part[w * 64 + lane] = acc;
            __syncthreads();

            if (tid < 64) {
                float s = b_t[tid];
                #pragma unroll
                for (int ww = 0; ww < 8; ++ww) s += part[ww * 64 + tid];
                ten[tid] = s > 0.f ? s : 0.f;
            }
            __syncthreads();

            {
                int j = tid;
                float gj = pg[(size_t)r * 512 + j];
                #pragma unroll 8
                for (int e = 0; e < 64; ++e)
                    gj = fmaf(ten[e], W_ihT[e * 512 + j], gj);
                #pragma unroll 8
                for (int hd = 0; hd < 128; ++hd)
                    gj = fmaf(hcur[hd], W_hhT[hd * 512 + j], gj);
                gts[j] = gj;
            }
            __syncthreads();

            if (tid < 128) {
                float ig = gts[tid], fg = gts[128 + tid], ggt = gts[256 + tid], og = gts[384 + tid];
                float si = 1.f / (1.f + expf(-ig));
                float sf = 1.f / (1.f + expf(-fg));
                float so = 1.f / (1.f + expf(-og));
                float cold = c[p * 128 + tid];
                float c2 = sf * cold + si * tanhf(ggt);
                float h2 = so * tanhf(c2);
                cn[p * 128 + tid] = c2;                 // block-local: normal store
                __hip_atomic_store(&hn[p * 128 + tid], h2, __ATOMIC_RELAXED,
                                   __HIP_MEMORY_SCOPE_AGENT);  // cross-block
                h2s[tid] = h2;
                if (t == T_STEPS - 1) {
                    out[25600 + p * 128 + tid] = h2;   // h_fin
                    out[58368 + p * 128 + tid] = c2;   // c_fin
                }
            }
            __syncthreads();

            if (w < 5) {
                float s = h2s[lane] * W_out[w * 128 + lane]
                        + h2s[lane + 64] * W_out[w * 128 + 64 + lane];
                #pragma unroll
                for (int off = 32; off > 0; off >>= 1) s += __shfl_xor(s, off);
                if (lane == 0) out[(size_t)r * 5 + w] = s + b_out[w];
            }
        }
        if (t != T_STEPS - 1) gbar(bar, 256u * (++barn));
    }
}

extern "C" void kernel_launch(void* const* d_in, const int* in_sizes, int n_in,
                              void* d_out, int out_size, void* d_ws, size_t ws_size,
                              hipStream_t stream) {
    (void)in_sizes; (void)n_in; (void)out_size; (void)ws_size;
    const float* scene  = (const float*)d_in[0];
    const float* grids  = (const float*)d_in[1];
    const float* hidden = (const float*)d_in[2];
    const float* cell   = (const float*)d_in[3];
    const float* W_in  = (const float*)d_in[5];
    const float* b_in  = (const float*)d_in[6];
    const float* W_t   = (const float*)d_in[7];
    const float* b_t   = (const float*)d_in[8];
    const float* W_ih  = (const float*)d_in[9];
    const float* b_ih  = (const float*)d_in[10];
    const float* W_hh  = (const float*)d_in[11];
    const float* b_hh  = (const float*)d_in[12];
    const float* W_out = (const float*)d_in[13];
    const float* b_out = (const float*)d_in[14];

    float* ws   = (float*)d_ws;
    float* hbuf = ws;                    // 2 x 32768
    float* cbuf = ws + 65536;            // 2 x 32768
    float* A    = ws + 131072;           // 256*4096
    float* pg   = ws + 1310720;          // 20*256*512
    float* WT   = ws + 3932160;          // W_ihT 64*512
    int*   counts = (int*)(ws + 3964928);             // 5120 ints
    unsigned short* gidx = (unsigned short*)(ws + 3970048); // 5120*1024 u16
    float* W_hhT = ws + 6591488;         // 128*512
    unsigned int* bar = (unsigned int*)(ws + 6657152); // own cache line
    float* outf = (float*)d_out;

    hipLaunchKernelGGL(kC, dim3(5120), dim3(256), 0, stream,
                       grids, counts, gidx, bar);
    hipLaunchKernelGGL(kP, dim3(1296), dim3(256), 0, stream,
                       scene, hidden, cell, W_in, b_in, W_ih, b_ih, b_hh, W_hh,
                       pg, hbuf, cbuf, WT, W_hhT);

    const int* counts_c = counts;
    const unsigned short* gidx_c = gidx;
    const float* WT_c = WT;
    const float* W_hhT_c = W_hhT;
    const float* pg_c = pg;
    void* args[] = {
        (void*)&counts_c, (void*)&gidx_c, (void*)&W_t, (void*)&pg_c,
        (void*)&WT_c, (void*)&W_hhT_c, (void*)&b_t, (void*)&W_out,
        (void*)&b_out, (void*)&hbuf, (void*)&cbuf, (void*)&A, (void*)&outf,
        (void*)&bar
    };
    hipLaunchCooperativeKernel((const void*)kStep, dim3(256), dim3(512),
                               args, 0, stream);
}

// Round 16
// 1118.593 us; speedup vs baseline: 1.9985x; 1.0907x over previous
//
#include <hip/hip_runtime.h>
#include <cstdint>
#include <cstddef>

#define T_STEPS 20
#define N_PED   256
#define NG      16384   /* N_PED*G2 floats per grid row */

// XOR-swizzled LDS index for 64-wide K tiles (k in 0..63), 4-float blocks.
__device__ __forceinline__ int swz64(int row, int k) {
    return row * 64 + ((((k >> 2) ^ (row & 15)) << 2) | (k & 3));
}

// device-scope (agent) relaxed helpers — per-instruction coherent
__device__ __forceinline__ void st_agent_f2(float* p, float a, float b) {
    union { float f[2]; unsigned long long u; } cv;
    cv.f[0] = a; cv.f[1] = b;
    __hip_atomic_store((unsigned long long*)p, cv.u, __ATOMIC_RELAXED,
                       __HIP_MEMORY_SCOPE_AGENT);
}
__device__ __forceinline__ void ld_agent_f4(const float* p, float4* out) {
    union { unsigned long long u[2]; float4 f; } cv;
    cv.u[0] = __hip_atomic_load((const unsigned long long*)p, __ATOMIC_RELAXED,
                                __HIP_MEMORY_SCOPE_AGENT);
    cv.u[1] = __hip_atomic_load((const unsigned long long*)p + 1, __ATOMIC_RELAXED,
                                __HIP_MEMORY_SCOPE_AGENT);
    *out = cv.f;
}
__device__ __forceinline__ float ld_agent_f(const float* p) {
    return __hip_atomic_load(p, __ATOMIC_RELAXED, __HIP_MEMORY_SCOPE_AGENT);
}
__device__ __forceinline__ unsigned ld_flag(const unsigned* p) {
    return __hip_atomic_load(p, __ATOMIC_RELAXED, __HIP_MEMORY_SCOPE_AGENT);
}
__device__ __forceinline__ void st_flag(unsigned* p, unsigned v) {
    __hip_atomic_store(p, v, __ATOMIC_RELAXED, __HIP_MEMORY_SCOPE_AGENT);
}

// ---------------- Kernel P: one-time precompute ----------------
__global__ __launch_bounds__(256) void kP(
    const float* __restrict__ scene, const float* __restrict__ hidden,
    const float* __restrict__ cell,  const float* __restrict__ W_in,
    const float* __restrict__ b_in,  const float* __restrict__ W_ih,
    const float* __restrict__ b_ih,  const float* __restrict__ b_hh,
    const float* __restrict__ W_hh,
    float* __restrict__ pg, float* __restrict__ h0, float* __restrict__ c0,
    float* __restrict__ W_ihT, float* __restrict__ W_hhT)
{
    int bid = blockIdx.x, tid = threadIdx.x;
    if (bid >= 1280) {
        int gid = (bid - 1280) * 256 + tid;
        for (int u = gid; u < 32768; u += 4096) {
            h0[u] = hidden[u];
            c0[u] = cell[u];
            int e = u >> 9, j = u & 511;
            W_ihT[u] = W_ih[j * 128 + 64 + e];
        }
        for (int u = gid; u < 65536; u += 4096) {
            int h = u >> 9, j = u & 511;
            W_hhT[u] = W_hh[j * 128 + h];
        }
        return;
    }
    __shared__ float ie[16 * 64];
    __shared__ float wih[128 * 65];
    int tb = bid >> 6;
    int p0 = ((bid >> 2) & 15) * 16;
    int j0 = (bid & 3) * 128;

    for (int k = 0; k < 8; ++k) {
        int fl = (tid + k * 256) * 4;
        int j_loc = fl >> 6, e0 = fl & 63;
        float4 v = *(const float4*)(W_ih + (size_t)(j0 + j_loc) * 128 + e0);
        wih[j_loc * 65 + e0 + 0] = v.x;
        wih[j_loc * 65 + e0 + 1] = v.y;
        wih[j_loc * 65 + e0 + 2] = v.z;
        wih[j_loc * 65 + e0 + 3] = v.w;
    }
    {
        int pp = tid >> 4, e0 = (tid & 15) * 4;
        size_t sbase = ((size_t)tb * N_PED + (p0 + pp)) * 3;
        float x = scene[sbase + 1];
        float y = scene[sbase + 2];
        #pragma unroll
        for (int i = 0; i < 4; ++i) {
            int e = e0 + i;
            float v = b_in[e] + x * W_in[e * 2 + 0] + y * W_in[e * 2 + 1];
            ie[pp * 64 + e] = v > 0.f ? v : 0.f;
        }
    }
    __syncthreads();
    for (int k = 0; k < 8; ++k) {
        int u = k * 256 + tid;
        int pp = u >> 7, j_loc = u & 127;
        int j = j0 + j_loc;
        float s = b_ih[j] + b_hh[j];
        #pragma unroll 8
        for (int e = 0; e < 64; ++e)
            s = fmaf(ie[pp * 64 + e], wih[j_loc * 65 + e], s);
        pg[((size_t)tb * N_PED + (p0 + pp)) * 512 + j] = s;
    }
}

// ---------------- Kernel C: one-time grid compaction (+ flag init) ----------
__global__ __launch_bounds__(256) void kC(
    const float* __restrict__ grids, int* __restrict__ counts,
    unsigned short* __restrict__ gidx,
    unsigned int* __restrict__ Aflag, unsigned int* __restrict__ hflag)
{
    int r = blockIdx.x;              // t*256+p
    int tid = threadIdx.x, lane = tid & 63, w = tid >> 6;
    if (r == 0) Aflag[tid] = 0u;     // 256 threads cover 256 flags
    if (r == 1) hflag[tid] = 0u;
    __shared__ unsigned short st[4][1024];
    __shared__ int wcnts[4];
    const float* row = grids + (size_t)r * NG;
    int wcnt = 0;
    for (int rd = 0; rd < 16; ++rd) {
        int fb = w * 4096 + rd * 256 + lane * 4;
        float4 v = *(const float4*)(row + fb);
        #pragma unroll
        for (int c = 0; c < 4; ++c) {
            float val = (c == 0) ? v.x : (c == 1) ? v.y : (c == 2) ? v.z : v.w;
            unsigned long long m = __ballot(val != 0.0f);
            if (val != 0.0f) {
                int pos = wcnt + (int)__popcll(m & ((1ull << lane) - 1ull));
                st[w][pos] = (unsigned short)(fb + c);
            }
            wcnt += (int)__popcll(m);
        }
    }
    if (lane == 0) wcnts[w] = wcnt;
    __syncthreads();
    int base = 0;
    #pragma unroll
    for (int i = 0; i < 4; ++i) if (i < w) base += wcnts[i];
    for (int k = lane; k < wcnt; k += 64)
        gidx[(size_t)r * 1024 + base + k] = st[w][k];
    if (tid == 0) counts[r] = wcnts[0] + wcnts[1] + wcnts[2] + wcnts[3];
}

// ---------------- kStep: fused 20-step recurrence (per-block flags, no RMW) ----
// Flags are monotone step counters: Aflag[b]=t+1 after block b's Phase A(t);
// hflag[p]=t+1 after block p's Phase B(t). A is double-buffered (parity t&1);
// safety: hflag[p]>=t+2 => Aflag[all]>=t+2 => hflag[all]>=t+1 => all reads of
// A[t&1] complete before Phase A(t+2) overwrites it.
__global__ __launch_bounds__(512) void kStep(
    const int* __restrict__ counts, const unsigned short* __restrict__ gidx,
    const float* __restrict__ W_t,  const float* __restrict__ pg,
    const float* __restrict__ W_ihT, const float* __restrict__ W_hhT,
    const float* __restrict__ b_t,  const float* __restrict__ W_out,
    const float* __restrict__ b_out,
    float* __restrict__ hbuf, float* __restrict__ cbuf,
    float* __restrict__ A0, float* __restrict__ A1,
    float* __restrict__ out,
    unsigned int* __restrict__ Aflag, unsigned int* __restrict__ hflag)
{
    __shared__ float smem[16384];   // 64 KB
    int bid = blockIdx.x, tid = threadIdx.x;
    int lane = tid & 63, w = tid >> 6;

    for (int t = 0; t < T_STEPS; ++t) {
        const float* h  = hbuf + (t & 1) * 32768;
        const float* c  = cbuf + (t & 1) * 32768;
        float*       hn = hbuf + ((t + 1) & 1) * 32768;
        float*       cn = cbuf + ((t + 1) & 1) * 32768;
        float*       Acur = (t & 1) ? A1 : A0;

        // ================= Phase A: A = h @ W_t-tile =================
        {
            int o0 = (bid >> 6) * 64, g = bid & 63;
            // stage W_t (read-only) FIRST — overlaps with the h-flag wait
            #pragma unroll
            for (int i = 0; i < 4; ++i) {
                int u = i * 512 + tid;           // 0..2047
                int kh = u >> 10, rem = u & 1023, e = rem >> 4, k4 = (rem & 15) * 4;
                float4 v = *(const float4*)(W_t + (size_t)e * 8192 + g * 128 + kh * 64 + k4);
                *(float4*)&smem[8192 + kh * 4096 + swz64(e, k4)] = v;
            }
            // wait for the 64 h-rows this block stages (producers of h[t])
            if (t > 0) {
                if (w == 0) {
                    unsigned tgt = (unsigned)t;
                    while (1) {
                        unsigned v = ld_flag(&hflag[o0 + lane]);
                        if (__all(v >= tgt)) break;
                        __builtin_amdgcn_s_sleep(1);
                    }
                }
            }
            __syncthreads();
            // stage h (sc1 — bypass possibly-stale L2)
            #pragma unroll
            for (int i = 0; i < 4; ++i) {
                int u = i * 512 + tid;           // 0..2047
                int kh = u >> 10, rem = u & 1023, r = rem >> 4, k4 = (rem & 15) * 4;
                float4 v;
                ld_agent_f4(h + (size_t)(o0 + r) * 128 + kh * 64 + k4, &v);
                *(float4*)&smem[kh * 4096 + swz64(r, k4)] = v;
            }
            __syncthreads();
            int kh = w >> 2, wq = w & 3;
            int wrow = (wq >> 1) * 32, wcol = (wq & 1) * 32;
            int lr = (lane >> 3) * 4, lc = (lane & 7) * 4;
            const float* hsb = &smem[kh * 4096];
            const float* wtb = &smem[8192 + kh * 4096];
            float acc[4][4] = {};
            #pragma unroll
            for (int k4i = 0; k4i < 16; ++k4i) {
                int kd = k4i * 4;
                float4 a[4], b[4];
                #pragma unroll
                for (int i = 0; i < 4; ++i) a[i] = *(const float4*)&hsb[swz64(wrow + lr + i, kd)];
                #pragma unroll
                for (int j = 0; j < 4; ++j) b[j] = *(const float4*)&wtb[swz64(wcol + lc + j, kd)];
                #pragma unroll
                for (int i = 0; i < 4; ++i)
                    #pragma unroll
                    for (int j = 0; j < 4; ++j) {
                        acc[i][j] = fmaf(a[i].x, b[j].x, acc[i][j]);
                        acc[i][j] = fmaf(a[i].y, b[j].y, acc[i][j]);
                        acc[i][j] = fmaf(a[i].z, b[j].z, acc[i][j]);
                        acc[i][j] = fmaf(a[i].w, b[j].w, acc[i][j]);
                    }
            }
            __syncthreads();
            if (kh == 1) {
                #pragma unroll
                for (int i = 0; i < 4; ++i) {
                    int row = wrow + lr + i;
                    int col = (wcol + lc) ^ (((row >> 2) & 7) << 3);
                    *(float4*)&smem[row * 64 + col] =
                        make_float4(acc[i][0], acc[i][1], acc[i][2], acc[i][3]);
                }
            }
            __syncthreads();
            if (kh == 0) {
                #pragma unroll
                for (int i = 0; i < 4; ++i) {
                    int row = wrow + lr + i;
                    int col = (wcol + lc) ^ (((row >> 2) & 7) << 3);
                    float4 r4 = *(const float4*)&smem[row * 64 + col];
                    float* dst = &Acur[(size_t)(o0 + row) * 4096 + g * 64 + wcol + lc];
                    st_agent_f2(dst + 0, acc[i][0] + r4.x, acc[i][1] + r4.y);
                    st_agent_f2(dst + 2, acc[i][2] + r4.z, acc[i][3] + r4.w);
                }
            }
            __syncthreads();   // drains all waves' vmcnt: A tile at L3
            if (tid == 0) st_flag(&Aflag[bid], (unsigned)(t + 1));
        }

        // ================= Phase B: sparse pool + gates + LSTM =================
        {
            int p = bid, r = t * N_PED + p;
            unsigned short* lidx = (unsigned short*)smem;   // 1024 u16
            float* part = smem + 512;                        // 8*64
            float* ten  = smem + 1024;                       // 64
            float* gts  = smem + 1088;                       // 512
            float* h2s  = smem + 1600;                       // 128
            float* hcur = smem + 1728;                       // 128
            int cnt = counts[r];
            // stage index list BEFORE the flag wait (read-only, overlaps poll)
            ((unsigned int*)lidx)[tid] = ((const unsigned int*)(gidx + (size_t)r * 1024))[tid];
            // wait: all 256 A tiles of this step done
            if (w == 0) {
                unsigned tgt = (unsigned)(t + 1);
                const unsigned* af = Aflag + lane * 4;
                while (1) {
                    unsigned v0 = ld_flag(af + 0), v1 = ld_flag(af + 1);
                    unsigned v2 = ld_flag(af + 2), v3 = ld_flag(af + 3);
                    unsigned m01 = v0 < v1 ? v0 : v1;
                    unsigned m23 = v2 < v3 ? v2 : v3;
                    unsigned mn  = m01 < m23 ? m01 : m23;
                    if (__all(mn >= tgt)) break;
                    __builtin_amdgcn_s_sleep(1);
                }
            }
            __syncthreads();
            if (tid < 128) hcur[tid] = ld_agent_f(&h[p * 128 + tid]);
            __syncthreads();

            float acc = 0.f;
            int k = w;
            for (; k + 56 < cnt; k += 64) {
                int i0 = lidx[k],      i1 = lidx[k + 8],  i2 = lidx[k + 16], i3 = lidx[k + 24];
                int i4 = lidx[k + 32], i5 = lidx[k + 40], i6 = lidx[k + 48], i7 = lidx[k + 56];
                float a0 = ld_agent_f(&Acur[(size_t)i0 * 64 + lane]);
                float a1 = ld_agent_f(&Acur[(size_t)i1 * 64 + lane]);
                float a2 = ld_agent_f(&Acur[(size_t)i2 * 64 + lane]);
                float a3 = ld_agent_f(&Acur[(size_t)i3 * 64 + lane]);
                float a4 = ld_agent_f(&Acur[(size_t)i4 * 64 + lane]);
                float a5 = ld_agent_f(&Acur[(size_t)i5 * 64 + lane]);
                float a6 = ld_agent_f(&Acur[(size_t)i6 * 64 + lane]);
                float a7 = ld_agent_f(&Acur[(size_t)i7 * 64 + lane]);
                acc += a0 + a1; acc += a2 + a3; acc += a4 + a5; acc += a6 + a7;
            }
            for (; k < cnt; k += 8)
                acc += ld_agent_f(&Acur[(size_t)lidx[k] * 64 + lane]);
            part[w * 64 + lane] = acc;
            __syncthreads();

            if (tid < 64) {
                float s = b_t[tid];
                #pragma unroll
                for (int ww = 0; ww < 8; ++ww) s += part[ww * 64 + tid];
                ten[tid] = s > 0.f ? s : 0.f;
            }
            __syncthreads();

            {
                int j = tid;
                float gj = pg[(size_t)r * 512 + j];
                #pragma unroll 8
                for (int e = 0; e < 64; ++e)
                    gj = fmaf(ten[e], W_ihT[e * 512 + j], gj);
                #pragma unroll 8
                for (int hd = 0; hd < 128; ++hd)
                    gj = fmaf(hcur[hd], W_hhT[hd * 512 + j], gj);
                gts[j] = gj;
            }
            __syncthreads();

            if (tid < 128) {
                float ig = gts[tid], fg = gts[128 + tid], ggt = gts[256 + tid], og = gts[384 + tid];
                float si = 1.f / (1.f + expf(-ig));
                float sf = 1.f / (1.f + expf(-fg));
                float so = 1.f / (1.f + expf(-og));
                float cold = c[p * 128 + tid];
                float c2 = sf * cold + si * tanhf(ggt);
                float h2 = so * tanhf(c2);
                cn[p * 128 + tid] = c2;                 // block-local: plain store
                __hip_atomic_store(&hn[p * 128 + tid], h2, __ATOMIC_RELAXED,
                                   __HIP_MEMORY_SCOPE_AGENT);  // cross-block
                h2s[tid] = h2;
                if (t == T_STEPS - 1) {
                    out[25600 + p * 128 + tid] = h2;   // h_fin
                    out[58368 + p * 128 + tid] = c2;   // c_fin
                }
            }
            __syncthreads();   // drains hn stores: h[t+1] row p at L3
            if (tid == 0) st_flag(&hflag[bid], (unsigned)(t + 1));

            if (w < 5) {
                float s = h2s[lane] * W_out[w * 128 + lane]
                        + h2s[lane + 64] * W_out[w * 128 + 64 + lane];
                #pragma unroll
                for (int off = 32; off > 0; off >>= 1) s += __shfl_xor(s, off);
                if (lane == 0) out[(size_t)r * 5 + w] = s + b_out[w];
            }
        }
    }
}

extern "C" void kernel_launch(void* const* d_in, const int* in_sizes, int n_in,
                              void* d_out, int out_size, void* d_ws, size_t ws_size,
                              hipStream_t stream) {
    (void)in_sizes; (void)n_in; (void)out_size; (void)ws_size;
    const float* scene  = (const float*)d_in[0];
    const float* grids  = (const float*)d_in[1];
    const float* hidden = (const float*)d_in[2];
    const float* cell   = (const float*)d_in[3];
    const float* W_in  = (const float*)d_in[5];
    const float* b_in  = (const float*)d_in[6];
    const float* W_t   = (const float*)d_in[7];
    const float* b_t   = (const float*)d_in[8];
    const float* W_ih  = (const float*)d_in[9];
    const float* b_ih  = (const float*)d_in[10];
    const float* W_hh  = (const float*)d_in[11];
    const float* b_hh  = (const float*)d_in[12];
    const float* W_out = (const float*)d_in[13];
    const float* b_out = (const float*)d_in[14];

    float* ws   = (float*)d_ws;
    float* hbuf = ws;                        // 2 x 32768
    float* cbuf = ws + 65536;                // 2 x 32768
    float* A0   = ws + 131072;               // 256*4096
    float* A1   = ws + 1179648;              // 256*4096
    float* pg   = ws + 2228224;              // 20*256*512
    float* WT   = ws + 4849664;              // W_ihT 64*512
    float* W_hhT= ws + 4882432;              // 128*512
    int*   counts = (int*)(ws + 4947968);    // 5120 ints
    unsigned short* gidx = (unsigned short*)(ws + 4953088); // 5120*1024 u16
    unsigned int* Aflag = (unsigned int*)(ws + 7574528);    // 256
    unsigned int* hflag = (unsigned int*)(ws + 7574784);    // 256
    float* outf = (float*)d_out;

    hipLaunchKernelGGL(kC, dim3(5120), dim3(256), 0, stream,
                       grids, counts, gidx, Aflag, hflag);
    hipLaunchKernelGGL(kP, dim3(1296), dim3(256), 0, stream,
                       scene, hidden, cell, W_in, b_in, W_ih, b_ih, b_hh, W_hh,
                       pg, hbuf, cbuf, WT, W_hhT);

    const int* counts_c = counts;
    const unsigned short* gidx_c = gidx;
    const float* WT_c = WT;
    const float* W_hhT_c = W_hhT;
    const float* pg_c = pg;
    void* args[] = {
        (void*)&counts_c, (void*)&gidx_c, (void*)&W_t, (void*)&pg_c,
        (void*)&WT_c, (void*)&W_hhT_c, (void*)&b_t, (void*)&W_out,
        (void*)&b_out, (void*)&hbuf, (void*)&cbuf, (void*)&A0, (void*)&A1,
        (void*)&outf, (void*)&Aflag, (void*)&hflag
    };
    hipLaunchCooperativeKernel((const void*)kStep, dim3(256), dim3(512),
                               args, 0, stream);
}